// Round 1
// 200.649 us; speedup vs baseline: 1.4799x; 1.4799x over previous
//
#include <hip/hip_runtime.h>
#include <math.h>

#define B   256
#define IU  8
#define IC  1152
#define NU  10
#define US  16
#define ROWS (B * IU)   // 2048

// ---------------- x transpose: x[b][i][c] -> xT[c][b*8+i] ----------------
// pure 2D transpose of [2048][1152] -> [1152][2048]; run once, ~2x9.4MB traffic
__global__ __launch_bounds__(256) void transpose_x(const float* __restrict__ x,
                                                   float* __restrict__ xT) {
    __shared__ float t[32][33];
    const int tx = threadIdx.x & 31, ty = threadIdx.x >> 5;
    const int ct = blockIdx.x % 36;   // 1152/32 col tiles
    const int rt = blockIdx.x / 36;   // 2048/32 row tiles
    const int c0 = ct * 32, r0 = rt * 32;
#pragma unroll
    for (int k = 0; k < 32; k += 8)
        t[ty + k][tx] = x[(size_t)(r0 + ty + k) * IC + c0 + tx];
    __syncthreads();
#pragma unroll
    for (int k = 0; k < 32; k += 8)
        xT[(size_t)(c0 + ty + k) * ROWS + r0 + tx] = t[tx][ty + k];
}

// ---------------- s pass ----------------
// s[b,d,u] = sum_{c,i} cT[d,c] * W[c,d,u,i] * x[b,i,c]
// grid 512 = 4 b-tiles (BT=64) x 128 c-chunks (CCH=9). Partials to sp[ch][b][d][u].
// Thread = (uq, bslot); each thread owns 4 batches (b = b0 + bs + 16*bb) and all 10 d.
// W + x both staged in LDS; inner loop is pure LDS reads + FMA (VALU-bound).
// W LDS layout [cc][d][half][uq] (float4): 16B-stride over uq => 2-way banks (free).
#define CCH 9
#define NCH 128
#define BT  64

__global__ __launch_bounds__(256) void s_pass(const float* __restrict__ xT,
                                              const float* __restrict__ W,
                                              const float* __restrict__ cT,
                                              float* __restrict__ sp) {
    __shared__ float4 ws[CCH * NU * 2 * 16];                 // 46080 B
    __shared__ __align__(16) float xs[CCH * BT * IU];        // 18432 B  [cc][bl][i]
    __shared__ float cs[NU * CCH];                           // 360 B
    const int tid = threadIdx.x;
    const int bt = blockIdx.x & 3;
    const int ch = blockIdx.x >> 2;
    const int b0 = bt * BT, c0 = ch * CCH;

    // stage W chunk: contiguous 2880 float4 from W + c0*1280, permuted [cc][d][u][h]->[cc][d][h][u]
    const float4* wg = (const float4*)W + (size_t)c0 * 320;
    for (int q = tid; q < CCH * NU * 32; q += 256) {
        int h = q & 1, u = (q >> 1) & 15, cd = q >> 5;
        ws[(cd * 2 + h) * 16 + u] = wg[q];
    }
    // stage x chunk: per cc a contiguous 512-float row of xT
    const float4* xg = (const float4*)xT;
    float4* xsv = (float4*)xs;
    for (int q = tid; q < CCH * BT * 2; q += 256) {
        int cc = q >> 7, r = q & 127;
        xsv[cc * 128 + r] = xg[(size_t)(c0 + cc) * (ROWS / 4) + b0 * 2 + r];
    }
    float scale;
    if (cT) {
        for (int q = tid; q < NU * CCH; q += 256)
            cs[q] = cT[(q / CCH) * IC + c0 + (q % CCH)];
        scale = 1.0f;
    } else {
        for (int q = tid; q < NU * CCH; q += 256) cs[q] = 1.0f;
        scale = 1.0f / (float)IC;   // softmax(0) is uniform
    }
    __syncthreads();

    const int uq = tid & 15;
    const int bs = tid >> 4;

    float acc[4][NU];
#pragma unroll
    for (int bb = 0; bb < 4; bb++)
#pragma unroll
        for (int d = 0; d < NU; d++) acc[bb][d] = 0.0f;

#pragma unroll 3
    for (int cc = 0; cc < CCH; cc++) {
        float4 xv0[4], xv1[4];
#pragma unroll
        for (int bb = 0; bb < 4; bb++) {
            // bslot stride 32B => 4 distinct addrs on distinct bank groups (conflict-free)
            const float4* xp = (const float4*)(xs + (cc * BT + bs + 16 * bb) * IU);
            xv0[bb] = xp[0]; xv1[bb] = xp[1];
        }
#pragma unroll
        for (int d = 0; d < NU; d++) {
            const float cw = cs[d * CCH + cc];
            float4 w0 = ws[((cc * NU + d) * 2 + 0) * 16 + uq];
            float4 w1 = ws[((cc * NU + d) * 2 + 1) * 16 + uq];
#pragma unroll
            for (int bb = 0; bb < 4; bb++) {
                float uh = w0.x * xv0[bb].x + w0.y * xv0[bb].y + w0.z * xv0[bb].z + w0.w * xv0[bb].w
                         + w1.x * xv1[bb].x + w1.y * xv1[bb].y + w1.z * xv1[bb].z + w1.w * xv1[bb].w;
                acc[bb][d] = fmaf(cw, uh, acc[bb][d]);
            }
        }
    }
#pragma unroll
    for (int bb = 0; bb < 4; bb++) {
        const int b = b0 + bs + 16 * bb;
#pragma unroll
        for (int d = 0; d < NU; d++)
            sp[(((size_t)ch * B + b) * NU + d) * US + uq] = acc[bb][d] * scale;
    }
}

// ---------------- squash ----------------
// reduce 128 c-chunk partials, then v[b,d,u] = s * msq/((1+msq)*sqrt(msq)), msq = sum_d s^2
__global__ __launch_bounds__(192) void squash_k(const float* __restrict__ sp,
                                                float* __restrict__ vout) {
    __shared__ float smag[NU * US];
    const int b = blockIdx.x;
    const int tid = threadIdx.x;
    const int d = tid >> 4, uq = tid & 15;
    float s = 0.0f;
    if (d < NU) {
#pragma unroll 8
        for (int chp = 0; chp < NCH; chp++)
            s += sp[(((size_t)chp * B + b) * NU + d) * US + uq];
        smag[d * US + uq] = s * s;
    }
    __syncthreads();
    if (d < NU) {
        float msq = 0.0f;
#pragma unroll
        for (int dd = 0; dd < NU; dd++) msq += smag[dd * US + uq];
        float f = msq / ((1.0f + msq) * sqrtf(msq));
        vout[((size_t)b * NU + d) * US + uq] = s * f;
    }
}

// ---------------- agree pass ----------------
// agree[c,d] = (1/B) sum_{b,u} (sum_i W[c,d,u,i]*x[b,i,c]) * v[b,d,u]
// grid 576 = 72 c-tiles (16c) x 8 b-chunks (32b). Thread = (uq, cl).
// W[c,d,u,:] is loop-invariant over b => hoisted into 80 registers/thread.
// Final u-reduction via 16-lane shuffle tree; partials to ap[bch][d][c].
#define ACT 16
#define ABT 32
#define NBCH 8

__global__ __launch_bounds__(256) void agree_k(const float* __restrict__ xT,
                                               const float* __restrict__ W,
                                               const float* __restrict__ v,
                                               float* __restrict__ ap) {
    __shared__ __align__(16) float xs[ABT * 132];   // [bl][cl*8+i], row padded to 132 floats
    __shared__ __align__(16) float vs[ABT * NU * US];
    const int tid = threadIdx.x;
    const int ct = blockIdx.x % 72;
    const int bch = blockIdx.x / 72;
    const int c0 = ct * ACT, b0 = bch * ABT;
    const int uq = tid & 15, cl = tid >> 4;

    // hoist W into registers (in flight during LDS staging below)
    const float4* wg = (const float4*)W + (size_t)(c0 + cl) * 320 + uq * 2;
    float4 wA[NU], wB[NU];
#pragma unroll
    for (int d = 0; d < NU; d++) { wA[d] = wg[d * 32]; wB[d] = wg[d * 32 + 1]; }

    const float4* xg = (const float4*)xT;
    for (int q = tid; q < ACT * ABT * 2; q += 256) {
        int h = q & 1, bl = (q >> 1) & 31, cc = q >> 6;
        float4 val = xg[(size_t)(c0 + cc) * (ROWS / 4) + (b0 + bl) * 2 + h];
        *(float4*)(xs + bl * 132 + cc * 8 + h * 4) = val;
    }
    const float4* vg = (const float4*)(v + (size_t)b0 * NU * US);
    float4* vsv = (float4*)vs;
    for (int q = tid; q < ABT * NU * US / 4; q += 256)
        vsv[q] = vg[q];
    __syncthreads();

    float acc[NU];
#pragma unroll
    for (int d = 0; d < NU; d++) acc[d] = 0.0f;

#pragma unroll 4
    for (int bl = 0; bl < ABT; bl++) {
        const float4* xp = (const float4*)(xs + bl * 132 + cl * 8);  // cl stride 32B: conflict-free
        float4 x0 = xp[0], x1 = xp[1];
        const float* vp = vs + bl * NU * US + uq;                    // uq stride 4B: conflict-free
#pragma unroll
        for (int d = 0; d < NU; d++) {
            float uh = wA[d].x * x0.x + wA[d].y * x0.y + wA[d].z * x0.z + wA[d].w * x0.w
                     + wB[d].x * x1.x + wB[d].y * x1.y + wB[d].z * x1.z + wB[d].w * x1.w;
            acc[d] = fmaf(uh, vp[d * 16], acc[d]);
        }
    }
#pragma unroll
    for (int d = 0; d < NU; d++) {
        float a = acc[d];
        a += __shfl_xor(a, 1, 64);
        a += __shfl_xor(a, 2, 64);
        a += __shfl_xor(a, 4, 64);
        a += __shfl_xor(a, 8, 64);
        if (uq == 0)
            ap[((size_t)bch * NU + d) * IC + c0 + cl] = a;
    }
}

// ---------------- b update + softmax over channels ----------------
// one block per d; reduces 8 agree partials, b += agree/B, cT[d,c] = softmax_c(b[d,c])
__global__ __launch_bounds__(384) void bsm_k(const float* __restrict__ ap,
                                             float* __restrict__ bij,
                                             float* __restrict__ cT,
                                             int first) {
    __shared__ float wred[8];
    __shared__ float bcast;
    const int d = blockIdx.x;
    const int tid = threadIdx.x;
    float bn[3];
    float lmax = -1e30f;
#pragma unroll
    for (int k = 0; k < 3; k++) {
        int c = tid + k * 384;
        float a = 0.0f;
#pragma unroll
        for (int g = 0; g < NBCH; g++) a += ap[((size_t)g * NU + d) * IC + c];
        a *= (1.0f / (float)B);
        float bo = first ? 0.0f : bij[d * IC + c];
        bn[k] = bo + a;
        bij[d * IC + c] = bn[k];
        lmax = fmaxf(lmax, bn[k]);
    }
    for (int off = 32; off > 0; off >>= 1) lmax = fmaxf(lmax, __shfl_down(lmax, off, 64));
    const int wid = tid >> 6, lane = tid & 63;
    if (lane == 0) wred[wid] = lmax;
    __syncthreads();
    if (tid == 0) {
        float m = wred[0];
        for (int w_ = 1; w_ < 6; w_++) m = fmaxf(m, wred[w_]);
        bcast = m;
    }
    __syncthreads();
    const float mx = bcast;
    float e[3];
    float lsum = 0.0f;
#pragma unroll
    for (int k = 0; k < 3; k++) { e[k] = expf(bn[k] - mx); lsum += e[k]; }
    for (int off = 32; off > 0; off >>= 1) lsum += __shfl_down(lsum, off, 64);
    if (lane == 0) wred[wid] = lsum;
    __syncthreads();
    if (tid == 0) {
        float s2 = 0.0f;
        for (int w_ = 0; w_ < 6; w_++) s2 += wred[w_];
        bcast = 1.0f / s2;
    }
    __syncthreads();
    const float inv = bcast;
#pragma unroll
    for (int k = 0; k < 3; k++) cT[d * IC + tid + k * 384] = e[k] * inv;
}

extern "C" void kernel_launch(void* const* d_in, const int* in_sizes, int n_in,
                              void* d_out, int out_size, void* d_ws, size_t ws_size,
                              hipStream_t stream) {
    (void)in_sizes; (void)n_in; (void)out_size; (void)ws_size;
    const float* x = (const float*)d_in[0];   // [256, 8, 1152]
    const float* W = (const float*)d_in[1];   // [1, 1152, 10, 16, 8]
    float* out = (float*)d_out;               // [256, 10, 16] fp32

    // workspace layout (floats): total 7,758,336 floats ~= 29.6 MiB
    float* xT  = (float*)d_ws;                       // 1152*2048 = 2,359,296
    float* sp  = xT + (size_t)IC * ROWS;             // 128*256*160 = 5,242,880
    float* v   = sp + (size_t)NCH * B * NU * US;     // 40,960
    float* bij = v + (size_t)B * NU * US;            // 11,520  [d][c]
    float* cTb = bij + (size_t)NU * IC;              // 11,520  [d][c]
    float* apg = cTb + (size_t)NU * IC;              // 8*10*1152 = 92,160

    transpose_x<<<36 * 64, 256, 0, stream>>>(x, xT);

    // iteration 1 (c uniform = 1/1152)
    s_pass<<<512, 256, 0, stream>>>(xT, W, nullptr, sp);
    squash_k<<<B, 192, 0, stream>>>(sp, v);
    agree_k<<<72 * NBCH, 256, 0, stream>>>(xT, W, v, apg);
    bsm_k<<<NU, 384, 0, stream>>>(apg, bij, cTb, 1);
    // iteration 2
    s_pass<<<512, 256, 0, stream>>>(xT, W, cTb, sp);
    squash_k<<<B, 192, 0, stream>>>(sp, v);
    agree_k<<<72 * NBCH, 256, 0, stream>>>(xT, W, v, apg);
    bsm_k<<<NU, 384, 0, stream>>>(apg, bij, cTb, 0);
    // iteration 3 (agree not needed after final squash)
    s_pass<<<512, 256, 0, stream>>>(xT, W, cTb, sp);
    squash_k<<<B, 192, 0, stream>>>(sp, out);
}